// Round 1
// baseline (5863.890 us; speedup 1.0000x reference)
//
#include <hip/hip_runtime.h>

// GCN-VAE encoder forward on MI355X.
// Pipeline:
//   cnt = in-degree(dst); dinv = rsqrt(1+cnt)
//   h1 = x @ w1                      (GEMM1, K=256, Ncol=128)
//   agg1 = scatter_dst(h1[src]*dinv[s]*dinv[d]) ; hidden = relu(agg1 + h1*dinv^2 + b1)
//   wcat = [w2 | w3]  (128x128), bcat = [b2 | b3]
//   h2 = hidden @ wcat               (GEMM2, K=128, Ncol=128)
//   agg2 = scatter_dst(h2[src]*coef) ; out = agg2 + h2*dinv^2 + bcat  -> split mu|logvar
//
// ws layout: bufA[N*128] | bufB[N*128] | cnt[N] | dinv[N] | wcat[128*128] | bcat[128]

#define TPB 256

// ---------------- degree ----------------
__global__ void count_kernel(const int* __restrict__ dst, int* __restrict__ cnt, int E) {
    int e = blockIdx.x * TPB + threadIdx.x;
    if (e < E) atomicAdd(&cnt[dst[e]], 1);
}

__global__ void dinv_kernel(const int* __restrict__ cnt, float* __restrict__ dinv, int N) {
    int i = blockIdx.x * TPB + threadIdx.x;
    if (i < N) dinv[i] = rsqrtf(1.0f + (float)cnt[i]);
}

// ---------------- weight concat ----------------
__global__ void prep_wcat(const float* __restrict__ w2, const float* __restrict__ b2,
                          const float* __restrict__ w3, const float* __restrict__ b3,
                          float* __restrict__ wcat, float* __restrict__ bcat) {
    int t = blockIdx.x * TPB + threadIdx.x;
    if (t < 128 * 64) {
        int k = t >> 6, j = t & 63;
        wcat[k * 128 + j]      = w2[t];
        wcat[k * 128 + 64 + j] = w3[t];
    }
    if (t < 64) { bcat[t] = b2[t]; bcat[64 + t] = b3[t]; }
}

// ---------------- f32 tiled GEMM, C[M,128] = A[M,K] @ B[K,128] ----------------
// BM=64, BN=128, BK=16; 256 threads as 16x16; TM=4 rows, TN=8 cols per thread.
__global__ __launch_bounds__(TPB) void gemm128(const float* __restrict__ A,
                                               const float* __restrict__ B,
                                               float* __restrict__ C, int M, int K) {
    const int BK = 16;
    __shared__ float As[BK][64 + 1];
    __shared__ float Bs[BK][128 + 4];
    int t = threadIdx.x;
    int tx = t & 15, ty = t >> 4;
    int bm0 = blockIdx.x * 64;

    float acc[4][8];
#pragma unroll
    for (int i = 0; i < 4; i++)
#pragma unroll
        for (int j = 0; j < 8; j++) acc[i][j] = 0.f;

    for (int k0 = 0; k0 < K; k0 += BK) {
        // A tile: 64 rows x 16 k — 1024 elems, 4/thread
#pragma unroll
        for (int it = 0; it < 4; ++it) {
            int idx = it * TPB + t;
            int row = idx >> 4, kk = idx & 15;
            int gr = bm0 + row;
            As[kk][row] = (gr < M) ? A[(size_t)gr * K + k0 + kk] : 0.f;
        }
        // B tile: 16 k x 128 cols — 2048 elems, 8/thread (coalesced over cols)
#pragma unroll
        for (int it = 0; it < 8; ++it) {
            int idx = it * TPB + t;
            int kk = idx >> 7, col = idx & 127;
            Bs[kk][col] = B[(size_t)(k0 + kk) * 128 + col];
        }
        __syncthreads();
#pragma unroll
        for (int kk = 0; kk < BK; ++kk) {
            float a[4], b[8];
#pragma unroll
            for (int i = 0; i < 4; i++) a[i] = As[kk][ty * 4 + i];
#pragma unroll
            for (int j = 0; j < 8; j++) b[j] = Bs[kk][tx * 8 + j];
#pragma unroll
            for (int i = 0; i < 4; i++)
#pragma unroll
                for (int j = 0; j < 8; j++) acc[i][j] += a[i] * b[j];
        }
        __syncthreads();
    }
#pragma unroll
    for (int i = 0; i < 4; i++) {
        int gr = bm0 + ty * 4 + i;
        if (gr < M) {
            float4* cp = (float4*)(C + (size_t)gr * 128 + tx * 8);
            cp[0] = make_float4(acc[i][0], acc[i][1], acc[i][2], acc[i][3]);
            cp[1] = make_float4(acc[i][4], acc[i][5], acc[i][6], acc[i][7]);
        }
    }
}

// ---------------- scatter: agg[dst] += h[src] * dinv[s]*dinv[d] (128 wide) ----------------
// One thread per (edge, 4 floats): 32 threads/edge, float4 load + 4 atomics.
__global__ __launch_bounds__(TPB) void scatter_kernel(const int* __restrict__ src,
                                                      const int* __restrict__ dst,
                                                      const float* __restrict__ dinv,
                                                      const float* __restrict__ h,
                                                      float* __restrict__ agg, int E) {
    size_t t = (size_t)blockIdx.x * TPB + threadIdx.x;
    if (t >= (size_t)E * 32) return;
    int e = (int)(t >> 5);
    int l = (int)(t & 31);
    int s = src[e], d = dst[e];
    float c = dinv[s] * dinv[d];
    float4 v = ((const float4*)(h + (size_t)s * 128))[l];
    float* ap = agg + (size_t)d * 128 + l * 4;
    atomicAdd(ap + 0, v.x * c);
    atomicAdd(ap + 1, v.y * c);
    atomicAdd(ap + 2, v.z * c);
    atomicAdd(ap + 3, v.w * c);
}

// ---------------- hidden = relu(agg + h1*dinv^2 + b1), in-place into agg ----------------
__global__ __launch_bounds__(TPB) void hidden_kernel(float* __restrict__ agg,
                                                     const float* __restrict__ h1,
                                                     const float* __restrict__ dinv,
                                                     const float* __restrict__ b1, int N) {
    size_t t = (size_t)blockIdx.x * TPB + threadIdx.x;
    if (t >= (size_t)N * 32) return;
    int i = (int)(t >> 5);
    int f4 = (int)(t & 31);
    float di = dinv[i];
    float c = di * di;
    float4 a = ((const float4*)agg)[t];
    float4 h = ((const float4*)h1)[t];
    float4 bb = ((const float4*)b1)[f4];
    float4 r;
    r.x = fmaxf(fmaf(h.x, c, a.x) + bb.x, 0.f);
    r.y = fmaxf(fmaf(h.y, c, a.y) + bb.y, 0.f);
    r.z = fmaxf(fmaf(h.z, c, a.z) + bb.z, 0.f);
    r.w = fmaxf(fmaf(h.w, c, a.w) + bb.w, 0.f);
    ((float4*)agg)[t] = r;
}

// ---------------- epilogue: out = agg + h2*dinv^2 + bcat, split mu | logvar ----------------
__global__ __launch_bounds__(TPB) void epilogue_kernel(const float* __restrict__ agg,
                                                       const float* __restrict__ h2,
                                                       const float* __restrict__ dinv,
                                                       const float* __restrict__ bcat,
                                                       float* __restrict__ out, int N) {
    size_t t = (size_t)blockIdx.x * TPB + threadIdx.x;
    if (t >= (size_t)N * 32) return;
    int i = (int)(t >> 5);
    int f4 = (int)(t & 31);
    float di = dinv[i];
    float c = di * di;
    float4 a = ((const float4*)agg)[t];
    float4 h = ((const float4*)h2)[t];
    float4 bb = ((const float4*)bcat)[f4];
    float4 r;
    r.x = fmaf(h.x, c, a.x) + bb.x;
    r.y = fmaf(h.y, c, a.y) + bb.y;
    r.z = fmaf(h.z, c, a.z) + bb.z;
    r.w = fmaf(h.w, c, a.w) + bb.w;
    int f = f4 * 4;  // 0..124
    float* dp = (f < 64) ? (out + (size_t)i * 64 + f)
                         : (out + (size_t)N * 64 + (size_t)i * 64 + (f - 64));
    *(float4*)dp = r;
}

extern "C" void kernel_launch(void* const* d_in, const int* in_sizes, int n_in,
                              void* d_out, int out_size, void* d_ws, size_t ws_size,
                              hipStream_t stream) {
    const float* x  = (const float*)d_in[0];
    const float* w1 = (const float*)d_in[1];
    const float* b1 = (const float*)d_in[2];
    const float* w2 = (const float*)d_in[3];
    const float* b2 = (const float*)d_in[4];
    const float* w3 = (const float*)d_in[5];
    const float* b3 = (const float*)d_in[6];
    const int*   ei = (const int*)d_in[7];

    const int N = in_sizes[0] / 256;   // 100000
    const int E = in_sizes[7] / 2;     // 1600000
    const int K1 = 256;

    float* out = (float*)d_out;

    // workspace carve-up
    size_t nh = (size_t)N * 128;
    float* bufA = (float*)d_ws;            // agg1 / hidden / agg2
    float* bufB = bufA + nh;               // h1 / h2
    int*   cnt  = (int*)(bufB + nh);
    float* dinv = (float*)(cnt + N);
    float* wcat = dinv + N;
    float* bcat = wcat + 128 * 128;

    const int* srcp = ei;
    const int* dstp = ei + E;

    size_t nbh = nh * sizeof(float);

    // 0) zero cnt + agg1
    hipMemsetAsync(cnt, 0, (size_t)N * sizeof(int), stream);
    hipMemsetAsync(bufA, 0, nbh, stream);

    // 1) degree + dinv
    count_kernel<<<(E + TPB - 1) / TPB, TPB, 0, stream>>>(dstp, cnt, E);
    dinv_kernel<<<(N + TPB - 1) / TPB, TPB, 0, stream>>>(cnt, dinv, N);

    // 2) h1 = x @ w1  -> bufB
    gemm128<<<(N + 63) / 64, TPB, 0, stream>>>(x, w1, bufB, N, K1);

    // 3) wcat/bcat
    prep_wcat<<<(128 * 64 + TPB - 1) / TPB, TPB, 0, stream>>>(w2, b2, w3, b3, wcat, bcat);

    // 4) agg1 += scatter(h1)  -> bufA
    size_t sthreads = (size_t)E * 32;
    scatter_kernel<<<(unsigned)((sthreads + TPB - 1) / TPB), TPB, 0, stream>>>(
        srcp, dstp, dinv, bufB, bufA, E);

    // 5) hidden = relu(agg1 + h1*dinv^2 + b1), in-place bufA
    size_t hthreads = (size_t)N * 32;
    hidden_kernel<<<(unsigned)((hthreads + TPB - 1) / TPB), TPB, 0, stream>>>(
        bufA, bufB, dinv, b1, N);

    // 6) h2 = hidden @ wcat -> bufB
    gemm128<<<(N + 63) / 64, TPB, 0, stream>>>(bufA, wcat, bufB, N, 128);

    // 7) zero agg2 (bufA reusable after gemm reads it; stream-ordered)
    hipMemsetAsync(bufA, 0, nbh, stream);

    // 8) agg2 += scatter(h2) -> bufA
    scatter_kernel<<<(unsigned)((sthreads + TPB - 1) / TPB), TPB, 0, stream>>>(
        srcp, dstp, dinv, bufB, bufA, E);

    // 9) out = agg2 + h2*dinv^2 + bcat -> mu | logvar
    epilogue_kernel<<<(unsigned)((hthreads + TPB - 1) / TPB), TPB, 0, stream>>>(
        bufA, bufB, dinv, bcat, out, N);
}

// Round 2
// 739.959 us; speedup vs baseline: 7.9246x; 7.9246x over previous
//
#include <hip/hip_runtime.h>

// GCN-VAE encoder forward on MI355X — R1: CSR-gather (no float atomics).
//
// Algebra: agg[d] = sum_{e:dst=d} h[s]*dinv[s]*dinv[d] + h[d]*dinv[d]^2
//                 = dinv[d] * ( hs[d] + sum_{s in N(d)} hs[s] ),  hs := h*dinv
// So GEMMs emit hs directly (row-scaled epilogue) and the gather fuses
// normalization + bias (+ReLU / output split).
//
// ws: bufA[N*128] | bufB[N*128] | cnt[N] | dinv[N] | rowptr[N] | cursor[N]
//     | bsum[512] | wcat[128*128] | bcat[128] | csr_src[E]

#define TPB 256

// ---------------- degree ----------------
__global__ void count_kernel(const int* __restrict__ dst, int* __restrict__ cnt, int E) {
    int e = blockIdx.x * TPB + threadIdx.x;
    if (e < E) atomicAdd(&cnt[dst[e]], 1);
}

__global__ void dinv_kernel(const int* __restrict__ cnt, float* __restrict__ dinv, int N) {
    int i = blockIdx.x * TPB + threadIdx.x;
    if (i < N) dinv[i] = rsqrtf(1.0f + (float)cnt[i]);
}

// ---------------- two-level exclusive scan (N <= 512*256) ----------------
__global__ void scan_block(const int* __restrict__ cnt, int* __restrict__ rowptr,
                           int* __restrict__ bsum, int N) {
    __shared__ int sh[TPB];
    int t = threadIdx.x;
    int i = blockIdx.x * TPB + t;
    int v = (i < N) ? cnt[i] : 0;
    sh[t] = v;
    __syncthreads();
#pragma unroll
    for (int off = 1; off < TPB; off <<= 1) {
        int x = (t >= off) ? sh[t - off] : 0;
        __syncthreads();
        sh[t] += x;
        __syncthreads();
    }
    if (i < N) rowptr[i] = sh[t] - v;  // exclusive
    if (t == TPB - 1) bsum[blockIdx.x] = sh[t];
}

__global__ void scan_bsum(int* __restrict__ bsum, int nb) {
    __shared__ int sh[512];
    int t = threadIdx.x;
    int v = (t < nb) ? bsum[t] : 0;
    sh[t] = v;
    __syncthreads();
#pragma unroll
    for (int off = 1; off < 512; off <<= 1) {
        int x = (t >= off) ? sh[t - off] : 0;
        __syncthreads();
        sh[t] += x;
        __syncthreads();
    }
    if (t < nb) bsum[t] = sh[t] - v;  // exclusive block offsets
}

__global__ void add_off(int* __restrict__ rowptr, const int* __restrict__ bsum, int N) {
    int i = blockIdx.x * TPB + threadIdx.x;
    if (i < N) rowptr[i] += bsum[blockIdx.x];
}

// ---------------- CSR fill ----------------
__global__ void fill_kernel(const int* __restrict__ src, const int* __restrict__ dst,
                            const int* __restrict__ rowptr, int* __restrict__ cursor,
                            int* __restrict__ csr, int E) {
    int e = blockIdx.x * TPB + threadIdx.x;
    if (e < E) {
        int d = dst[e];
        int p = rowptr[d] + atomicAdd(&cursor[d], 1);
        csr[p] = src[e];
    }
}

// ---------------- weight concat ----------------
__global__ void prep_wcat(const float* __restrict__ w2, const float* __restrict__ b2,
                          const float* __restrict__ w3, const float* __restrict__ b3,
                          float* __restrict__ wcat, float* __restrict__ bcat) {
    int t = blockIdx.x * TPB + threadIdx.x;
    if (t < 128 * 64) {
        int k = t >> 6, j = t & 63;
        wcat[k * 128 + j]      = w2[t];
        wcat[k * 128 + 64 + j] = w3[t];
    }
    if (t < 64) { bcat[t] = b2[t]; bcat[64 + t] = b3[t]; }
}

// ---------------- f32 tiled GEMM, C[M,128] = (A[M,K] @ B[K,128]) * rs[row] ----------------
__global__ __launch_bounds__(TPB) void gemm128(const float* __restrict__ A,
                                               const float* __restrict__ B,
                                               const float* __restrict__ rs,
                                               float* __restrict__ C, int M, int K) {
    const int BK = 16;
    __shared__ float As[BK][64 + 1];
    __shared__ float Bs[BK][128 + 4];
    int t = threadIdx.x;
    int tx = t & 15, ty = t >> 4;
    int bm0 = blockIdx.x * 64;

    float acc[4][8];
#pragma unroll
    for (int i = 0; i < 4; i++)
#pragma unroll
        for (int j = 0; j < 8; j++) acc[i][j] = 0.f;

    for (int k0 = 0; k0 < K; k0 += BK) {
#pragma unroll
        for (int it = 0; it < 4; ++it) {
            int idx = it * TPB + t;
            int row = idx >> 4, kk = idx & 15;
            int gr = bm0 + row;
            As[kk][row] = (gr < M) ? A[(size_t)gr * K + k0 + kk] : 0.f;
        }
#pragma unroll
        for (int it = 0; it < 8; ++it) {
            int idx = it * TPB + t;
            int kk = idx >> 7, col = idx & 127;
            Bs[kk][col] = B[(size_t)(k0 + kk) * 128 + col];
        }
        __syncthreads();
#pragma unroll
        for (int kk = 0; kk < BK; ++kk) {
            float a[4], b[8];
#pragma unroll
            for (int i = 0; i < 4; i++) a[i] = As[kk][ty * 4 + i];
#pragma unroll
            for (int j = 0; j < 8; j++) b[j] = Bs[kk][tx * 8 + j];
#pragma unroll
            for (int i = 0; i < 4; i++)
#pragma unroll
                for (int j = 0; j < 8; j++) acc[i][j] += a[i] * b[j];
        }
        __syncthreads();
    }
#pragma unroll
    for (int i = 0; i < 4; i++) {
        int gr = bm0 + ty * 4 + i;
        if (gr < M) {
            float s = rs[gr];
            float4* cp = (float4*)(C + (size_t)gr * 128 + tx * 8);
            cp[0] = make_float4(acc[i][0] * s, acc[i][1] * s, acc[i][2] * s, acc[i][3] * s);
            cp[1] = make_float4(acc[i][4] * s, acc[i][5] * s, acc[i][6] * s, acc[i][7] * s);
        }
    }
}

// ---------------- gather layer 1: hidden = relu(dinv*(hs[self]+sum hs[nbr]) + b1) ----------------
// one wave (64 lanes) per node; lane covers float2 of the 128-wide row.
__global__ __launch_bounds__(TPB) void gather_hidden(const int* __restrict__ csr,
                                                     const int* __restrict__ rowptr,
                                                     const int* __restrict__ cnt,
                                                     const float* __restrict__ dinv,
                                                     const float* __restrict__ hs,
                                                     const float* __restrict__ b1,
                                                     float* __restrict__ hidden, int N) {
    int nid = (int)(((size_t)blockIdx.x * TPB + threadIdx.x) >> 6);
    int lane = threadIdx.x & 63;
    if (nid >= N) return;
    int start = rowptr[nid];
    int deg = cnt[nid];
    const float2* hp = (const float2*)hs;
    float2 acc = hp[(size_t)nid * 64 + lane];  // self term
    int j = 0;
    for (; j + 1 < deg; j += 2) {
        int s0 = csr[start + j];
        int s1 = csr[start + j + 1];
        float2 v0 = hp[(size_t)s0 * 64 + lane];
        float2 v1 = hp[(size_t)s1 * 64 + lane];
        acc.x += v0.x + v1.x;
        acc.y += v0.y + v1.y;
    }
    if (j < deg) {
        int s = csr[start + j];
        float2 v = hp[(size_t)s * 64 + lane];
        acc.x += v.x;
        acc.y += v.y;
    }
    float di = dinv[nid];
    float2 bb = ((const float2*)b1)[lane];
    float2 r;
    r.x = fmaxf(fmaf(di, acc.x, bb.x), 0.f);
    r.y = fmaxf(fmaf(di, acc.y, bb.y), 0.f);
    ((float2*)hidden)[(size_t)nid * 64 + lane] = r;
}

// ---------------- gather layer 2: out = dinv*(hs[self]+sum hs[nbr]) + bcat, split mu|logvar ----------------
__global__ __launch_bounds__(TPB) void gather_out(const int* __restrict__ csr,
                                                  const int* __restrict__ rowptr,
                                                  const int* __restrict__ cnt,
                                                  const float* __restrict__ dinv,
                                                  const float* __restrict__ hs,
                                                  const float* __restrict__ bcat,
                                                  float* __restrict__ out, int N) {
    int nid = (int)(((size_t)blockIdx.x * TPB + threadIdx.x) >> 6);
    int lane = threadIdx.x & 63;
    if (nid >= N) return;
    int start = rowptr[nid];
    int deg = cnt[nid];
    const float2* hp = (const float2*)hs;
    float2 acc = hp[(size_t)nid * 64 + lane];  // self term
    int j = 0;
    for (; j + 1 < deg; j += 2) {
        int s0 = csr[start + j];
        int s1 = csr[start + j + 1];
        float2 v0 = hp[(size_t)s0 * 64 + lane];
        float2 v1 = hp[(size_t)s1 * 64 + lane];
        acc.x += v0.x + v1.x;
        acc.y += v0.y + v1.y;
    }
    if (j < deg) {
        int s = csr[start + j];
        float2 v = hp[(size_t)s * 64 + lane];
        acc.x += v.x;
        acc.y += v.y;
    }
    float di = dinv[nid];
    float2 bb = ((const float2*)bcat)[lane];
    float2 r;
    r.x = fmaf(di, acc.x, bb.x);
    r.y = fmaf(di, acc.y, bb.y);
    int f = lane * 2;  // 0..126
    float* dp = (f < 64) ? (out + (size_t)nid * 64 + f)
                         : (out + (size_t)N * 64 + (size_t)nid * 64 + (f - 64));
    *(float2*)dp = r;
}

extern "C" void kernel_launch(void* const* d_in, const int* in_sizes, int n_in,
                              void* d_out, int out_size, void* d_ws, size_t ws_size,
                              hipStream_t stream) {
    const float* x  = (const float*)d_in[0];
    const float* w1 = (const float*)d_in[1];
    const float* b1 = (const float*)d_in[2];
    const float* w2 = (const float*)d_in[3];
    const float* b2 = (const float*)d_in[4];
    const float* w3 = (const float*)d_in[5];
    const float* b3 = (const float*)d_in[6];
    const int*   ei = (const int*)d_in[7];

    const int N = in_sizes[0] / 256;   // 100000
    const int E = in_sizes[7] / 2;     // 1600000
    const int K1 = 256;
    const int nb = (N + TPB - 1) / TPB;  // scan blocks (391 <= 512)

    float* out = (float*)d_out;

    // workspace carve-up
    size_t nh = (size_t)N * 128;
    float* bufA   = (float*)d_ws;          // hidden
    float* bufB   = bufA + nh;             // hs1 / hs2
    int*   cnt    = (int*)(bufB + nh);
    float* dinv   = (float*)(cnt + N);
    int*   rowptr = (int*)(dinv + N);
    int*   cursor = rowptr + N;
    int*   bsum   = cursor + N;
    float* wcat   = (float*)(bsum + 512);
    float* bcat   = wcat + 128 * 128;
    int*   csr    = (int*)(bcat + 128);

    const int* srcp = ei;
    const int* dstp = ei + E;

    // 0) zero counters
    hipMemsetAsync(cnt, 0, (size_t)N * sizeof(int), stream);
    hipMemsetAsync(cursor, 0, (size_t)N * sizeof(int), stream);

    // 1) degree + dinv
    count_kernel<<<(E + TPB - 1) / TPB, TPB, 0, stream>>>(dstp, cnt, E);
    dinv_kernel<<<(N + TPB - 1) / TPB, TPB, 0, stream>>>(cnt, dinv, N);

    // 2) CSR build
    scan_block<<<nb, TPB, 0, stream>>>(cnt, rowptr, bsum, N);
    scan_bsum<<<1, 512, 0, stream>>>(bsum, nb);
    add_off<<<nb, TPB, 0, stream>>>(rowptr, bsum, N);
    fill_kernel<<<(E + TPB - 1) / TPB, TPB, 0, stream>>>(srcp, dstp, rowptr, cursor, csr, E);

    // 3) wcat/bcat
    prep_wcat<<<(128 * 64 + TPB - 1) / TPB, TPB, 0, stream>>>(w2, b2, w3, b3, wcat, bcat);

    // 4) hs1 = (x @ w1) * dinv  -> bufB
    gemm128<<<(N + 63) / 64, TPB, 0, stream>>>(x, w1, dinv, bufB, N, K1);

    // 5) hidden = relu(dinv*(self+nbrs) + b1) -> bufA
    size_t gthreads = (size_t)N * 64;
    gather_hidden<<<(unsigned)((gthreads + TPB - 1) / TPB), TPB, 0, stream>>>(
        csr, rowptr, cnt, dinv, bufB, b1, bufA, N);

    // 6) hs2 = (hidden @ wcat) * dinv -> bufB
    gemm128<<<(N + 63) / 64, TPB, 0, stream>>>(bufA, wcat, dinv, bufB, N, 128);

    // 7) out = dinv*(self+nbrs) + bcat -> mu | logvar
    gather_out<<<(unsigned)((gthreads + TPB - 1) / TPB), TPB, 0, stream>>>(
        csr, rowptr, cnt, dinv, bufB, bcat, out, N);
}

// Round 3
// 724.823 us; speedup vs baseline: 8.0901x; 1.0209x over previous
//
#include <hip/hip_runtime.h>

// GCN-VAE encoder forward on MI355X — R2: conflict-free 128x128x16 f32 GEMM
// (8x8 micro-tile, register prefetch) + float4 half-wave gathers.
//
// Algebra: agg[d] = dinv[d] * ( hs[d] + sum_{s in N(d)} hs[s] ),  hs := h*dinv
//
// ws: bufA[N*128] | bufB[N*128] | cnt[N] | dinv[N] | rowptr[N] | cursor[N]
//     | bsum[512] | wcat[128*128] | bcat[128] | csr_src[E]

#define TPB 256

// ---------------- degree ----------------
__global__ void count_kernel(const int* __restrict__ dst, int* __restrict__ cnt, int E) {
    int e = blockIdx.x * TPB + threadIdx.x;
    if (e < E) atomicAdd(&cnt[dst[e]], 1);
}

__global__ void dinv_kernel(const int* __restrict__ cnt, float* __restrict__ dinv, int N) {
    int i = blockIdx.x * TPB + threadIdx.x;
    if (i < N) dinv[i] = rsqrtf(1.0f + (float)cnt[i]);
}

// ---------------- two-level exclusive scan (N <= 512*256) ----------------
__global__ void scan_block(const int* __restrict__ cnt, int* __restrict__ rowptr,
                           int* __restrict__ bsum, int N) {
    __shared__ int sh[TPB];
    int t = threadIdx.x;
    int i = blockIdx.x * TPB + t;
    int v = (i < N) ? cnt[i] : 0;
    sh[t] = v;
    __syncthreads();
#pragma unroll
    for (int off = 1; off < TPB; off <<= 1) {
        int x = (t >= off) ? sh[t - off] : 0;
        __syncthreads();
        sh[t] += x;
        __syncthreads();
    }
    if (i < N) rowptr[i] = sh[t] - v;  // exclusive
    if (t == TPB - 1) bsum[blockIdx.x] = sh[t];
}

__global__ void scan_bsum(int* __restrict__ bsum, int nb) {
    __shared__ int sh[512];
    int t = threadIdx.x;
    int v = (t < nb) ? bsum[t] : 0;
    sh[t] = v;
    __syncthreads();
#pragma unroll
    for (int off = 1; off < 512; off <<= 1) {
        int x = (t >= off) ? sh[t - off] : 0;
        __syncthreads();
        sh[t] += x;
        __syncthreads();
    }
    if (t < nb) bsum[t] = sh[t] - v;  // exclusive block offsets
}

__global__ void add_off(int* __restrict__ rowptr, const int* __restrict__ bsum, int N) {
    int i = blockIdx.x * TPB + threadIdx.x;
    if (i < N) rowptr[i] += bsum[blockIdx.x];
}

// ---------------- CSR fill ----------------
__global__ void fill_kernel(const int* __restrict__ src, const int* __restrict__ dst,
                            const int* __restrict__ rowptr, int* __restrict__ cursor,
                            int* __restrict__ csr, int E) {
    int e = blockIdx.x * TPB + threadIdx.x;
    if (e < E) {
        int d = dst[e];
        int p = rowptr[d] + atomicAdd(&cursor[d], 1);
        csr[p] = src[e];
    }
}

// ---------------- weight concat ----------------
__global__ void prep_wcat(const float* __restrict__ w2, const float* __restrict__ b2,
                          const float* __restrict__ w3, const float* __restrict__ b3,
                          float* __restrict__ wcat, float* __restrict__ bcat) {
    int t = blockIdx.x * TPB + threadIdx.x;
    if (t < 128 * 64) {
        int k = t >> 6, j = t & 63;
        wcat[k * 128 + j]      = w2[t];
        wcat[k * 128 + 64 + j] = w3[t];
    }
    if (t < 64) { bcat[t] = b2[t]; bcat[64 + t] = b3[t]; }
}

// ---------------- f32 GEMM: C[M,128] = (A[M,K] @ B[K,128]) * rs[row] ----------------
// BM=128, BN=128, BK=16; 256 threads as 16x16; 8x8 micro-tile per thread,
// N/M each split into two float4 chunks at {q*4, 64+q*4} -> 2-way LDS aliasing (free).
__global__ __launch_bounds__(TPB) void gemm_f32(const float* __restrict__ A,
                                                const float* __restrict__ B,
                                                const float* __restrict__ rs,
                                                float* __restrict__ C, int M, int K) {
    const int BK = 16;
    __shared__ float As[BK][128 + 4];  // transposed: As[k][row]
    __shared__ float Bs[BK][128 + 4];  // Bs[k][col]
    int t = threadIdx.x;
    int tx = t & 15, ty = t >> 4;
    int bm0 = blockIdx.x * 128;

    float acc[8][8];
#pragma unroll
    for (int i = 0; i < 8; i++)
#pragma unroll
        for (int j = 0; j < 8; j++) acc[i][j] = 0.f;

    // per-thread load coords (2 float4 each for A and B)
    int arow[2], akc[2], bkk[2], bcol[2];
#pragma unroll
    for (int i = 0; i < 2; ++i) {
        int f = t + i * 256;
        arow[i] = f >> 2;
        akc[i] = (f & 3) * 4;
        bkk[i] = f >> 5;
        bcol[i] = (f & 31) * 4;
    }

    float4 av[2], bv[2];
    // prefetch first tile
#pragma unroll
    for (int i = 0; i < 2; ++i) {
        int gr = bm0 + arow[i];
        av[i] = (gr < M) ? *(const float4*)(A + (size_t)gr * K + akc[i])
                         : make_float4(0.f, 0.f, 0.f, 0.f);
        bv[i] = *(const float4*)(B + (size_t)bkk[i] * 128 + bcol[i]);
    }

    for (int k0 = 0; k0 < K; k0 += BK) {
        // store staged regs to LDS
#pragma unroll
        for (int i = 0; i < 2; ++i) {
            As[akc[i] + 0][arow[i]] = av[i].x;
            As[akc[i] + 1][arow[i]] = av[i].y;
            As[akc[i] + 2][arow[i]] = av[i].z;
            As[akc[i] + 3][arow[i]] = av[i].w;
            *(float4*)&Bs[bkk[i]][bcol[i]] = bv[i];
        }
        __syncthreads();
        // prefetch next tile into regs (overlaps compute below)
        int kn = k0 + BK;
        if (kn < K) {
#pragma unroll
            for (int i = 0; i < 2; ++i) {
                int gr = bm0 + arow[i];
                av[i] = (gr < M) ? *(const float4*)(A + (size_t)gr * K + kn + akc[i])
                                 : make_float4(0.f, 0.f, 0.f, 0.f);
                bv[i] = *(const float4*)(B + (size_t)(kn + bkk[i]) * 128 + bcol[i]);
            }
        }
#pragma unroll
        for (int kk = 0; kk < BK; ++kk) {
            float4 a0 = *(const float4*)&As[kk][ty * 4];
            float4 a1 = *(const float4*)&As[kk][64 + ty * 4];
            float4 b0 = *(const float4*)&Bs[kk][tx * 4];
            float4 b1 = *(const float4*)&Bs[kk][64 + tx * 4];
            float a[8] = {a0.x, a0.y, a0.z, a0.w, a1.x, a1.y, a1.z, a1.w};
            float b[8] = {b0.x, b0.y, b0.z, b0.w, b1.x, b1.y, b1.z, b1.w};
#pragma unroll
            for (int i = 0; i < 8; i++)
#pragma unroll
                for (int j = 0; j < 8; j++) acc[i][j] = fmaf(a[i], b[j], acc[i][j]);
        }
        __syncthreads();
    }

    // epilogue: rows {ty*4+i, 64+ty*4+i}, cols {tx*4, 64+tx*4}
#pragma unroll
    for (int h = 0; h < 2; ++h) {
#pragma unroll
        for (int i = 0; i < 4; ++i) {
            int gr = bm0 + h * 64 + ty * 4 + i;
            if (gr < M) {
                float s = rs[gr];
                float* cp = C + (size_t)gr * 128;
                int ii = h * 4 + i;
                *(float4*)(cp + tx * 4) = make_float4(acc[ii][0] * s, acc[ii][1] * s,
                                                      acc[ii][2] * s, acc[ii][3] * s);
                *(float4*)(cp + 64 + tx * 4) = make_float4(acc[ii][4] * s, acc[ii][5] * s,
                                                           acc[ii][6] * s, acc[ii][7] * s);
            }
        }
    }
}

// ---------------- gather layer 1: hidden = relu(dinv*(hs[self]+sum hs[nbr]) + b1) ----------------
// 32 lanes per node, float4 per lane.
__global__ __launch_bounds__(TPB) void gather_hidden(const int* __restrict__ csr,
                                                     const int* __restrict__ rowptr,
                                                     const int* __restrict__ cnt,
                                                     const float* __restrict__ dinv,
                                                     const float* __restrict__ hs,
                                                     const float* __restrict__ b1,
                                                     float* __restrict__ hidden, int N) {
    size_t t = (size_t)blockIdx.x * TPB + threadIdx.x;
    int nid = (int)(t >> 5);
    int lane = threadIdx.x & 31;
    if (nid >= N) return;
    int start = rowptr[nid];
    int deg = cnt[nid];
    const float4* hp = (const float4*)hs;
    float4 acc = hp[(size_t)nid * 32 + lane];  // self term
    int j = 0;
    for (; j + 3 < deg; j += 4) {
        int s0 = csr[start + j], s1 = csr[start + j + 1];
        int s2 = csr[start + j + 2], s3 = csr[start + j + 3];
        float4 v0 = hp[(size_t)s0 * 32 + lane];
        float4 v1 = hp[(size_t)s1 * 32 + lane];
        float4 v2 = hp[(size_t)s2 * 32 + lane];
        float4 v3 = hp[(size_t)s3 * 32 + lane];
        acc.x += (v0.x + v1.x) + (v2.x + v3.x);
        acc.y += (v0.y + v1.y) + (v2.y + v3.y);
        acc.z += (v0.z + v1.z) + (v2.z + v3.z);
        acc.w += (v0.w + v1.w) + (v2.w + v3.w);
    }
    for (; j < deg; ++j) {
        int s = csr[start + j];
        float4 v = hp[(size_t)s * 32 + lane];
        acc.x += v.x; acc.y += v.y; acc.z += v.z; acc.w += v.w;
    }
    float di = dinv[nid];
    float4 bb = ((const float4*)b1)[lane];
    float4 r;
    r.x = fmaxf(fmaf(di, acc.x, bb.x), 0.f);
    r.y = fmaxf(fmaf(di, acc.y, bb.y), 0.f);
    r.z = fmaxf(fmaf(di, acc.z, bb.z), 0.f);
    r.w = fmaxf(fmaf(di, acc.w, bb.w), 0.f);
    ((float4*)hidden)[(size_t)nid * 32 + lane] = r;
}

// ---------------- gather layer 2: out = dinv*(hs[self]+sum hs[nbr]) + bcat, split mu|logvar ----------------
__global__ __launch_bounds__(TPB) void gather_out(const int* __restrict__ csr,
                                                  const int* __restrict__ rowptr,
                                                  const int* __restrict__ cnt,
                                                  const float* __restrict__ dinv,
                                                  const float* __restrict__ hs,
                                                  const float* __restrict__ bcat,
                                                  float* __restrict__ out, int N) {
    size_t t = (size_t)blockIdx.x * TPB + threadIdx.x;
    int nid = (int)(t >> 5);
    int lane = threadIdx.x & 31;
    if (nid >= N) return;
    int start = rowptr[nid];
    int deg = cnt[nid];
    const float4* hp = (const float4*)hs;
    float4 acc = hp[(size_t)nid * 32 + lane];  // self term
    int j = 0;
    for (; j + 3 < deg; j += 4) {
        int s0 = csr[start + j], s1 = csr[start + j + 1];
        int s2 = csr[start + j + 2], s3 = csr[start + j + 3];
        float4 v0 = hp[(size_t)s0 * 32 + lane];
        float4 v1 = hp[(size_t)s1 * 32 + lane];
        float4 v2 = hp[(size_t)s2 * 32 + lane];
        float4 v3 = hp[(size_t)s3 * 32 + lane];
        acc.x += (v0.x + v1.x) + (v2.x + v3.x);
        acc.y += (v0.y + v1.y) + (v2.y + v3.y);
        acc.z += (v0.z + v1.z) + (v2.z + v3.z);
        acc.w += (v0.w + v1.w) + (v2.w + v3.w);
    }
    for (; j < deg; ++j) {
        int s = csr[start + j];
        float4 v = hp[(size_t)s * 32 + lane];
        acc.x += v.x; acc.y += v.y; acc.z += v.z; acc.w += v.w;
    }
    float di = dinv[nid];
    float4 bb = ((const float4*)bcat)[lane];
    float4 r;
    r.x = fmaf(di, acc.x, bb.x);
    r.y = fmaf(di, acc.y, bb.y);
    r.z = fmaf(di, acc.z, bb.z);
    r.w = fmaf(di, acc.w, bb.w);
    int f = lane * 4;  // 0..124
    float* dp = (f < 64) ? (out + (size_t)nid * 64 + f)
                         : (out + (size_t)N * 64 + (size_t)nid * 64 + (f - 64));
    *(float4*)dp = r;
}

extern "C" void kernel_launch(void* const* d_in, const int* in_sizes, int n_in,
                              void* d_out, int out_size, void* d_ws, size_t ws_size,
                              hipStream_t stream) {
    const float* x  = (const float*)d_in[0];
    const float* w1 = (const float*)d_in[1];
    const float* b1 = (const float*)d_in[2];
    const float* w2 = (const float*)d_in[3];
    const float* b2 = (const float*)d_in[4];
    const float* w3 = (const float*)d_in[5];
    const float* b3 = (const float*)d_in[6];
    const int*   ei = (const int*)d_in[7];

    const int N = in_sizes[0] / 256;   // 100000
    const int E = in_sizes[7] / 2;     // 1600000
    const int K1 = 256;
    const int nb = (N + TPB - 1) / TPB;  // scan blocks (391 <= 512)

    float* out = (float*)d_out;

    // workspace carve-up
    size_t nh = (size_t)N * 128;
    float* bufA   = (float*)d_ws;          // hidden
    float* bufB   = bufA + nh;             // hs1 / hs2
    int*   cnt    = (int*)(bufB + nh);
    float* dinv   = (float*)(cnt + N);
    int*   rowptr = (int*)(dinv + N);
    int*   cursor = rowptr + N;
    int*   bsum   = cursor + N;
    float* wcat   = (float*)(bsum + 512);
    float* bcat   = wcat + 128 * 128;
    int*   csr    = (int*)(bcat + 128);

    const int* srcp = ei;
    const int* dstp = ei + E;

    // 0) zero counters
    hipMemsetAsync(cnt, 0, (size_t)N * sizeof(int), stream);
    hipMemsetAsync(cursor, 0, (size_t)N * sizeof(int), stream);

    // 1) degree + dinv
    count_kernel<<<(E + TPB - 1) / TPB, TPB, 0, stream>>>(dstp, cnt, E);
    dinv_kernel<<<(N + TPB - 1) / TPB, TPB, 0, stream>>>(cnt, dinv, N);

    // 2) CSR build
    scan_block<<<nb, TPB, 0, stream>>>(cnt, rowptr, bsum, N);
    scan_bsum<<<1, 512, 0, stream>>>(bsum, nb);
    add_off<<<nb, TPB, 0, stream>>>(rowptr, bsum, N);
    fill_kernel<<<(E + TPB - 1) / TPB, TPB, 0, stream>>>(srcp, dstp, rowptr, cursor, csr, E);

    // 3) wcat/bcat
    prep_wcat<<<(128 * 64 + TPB - 1) / TPB, TPB, 0, stream>>>(w2, b2, w3, b3, wcat, bcat);

    // 4) hs1 = (x @ w1) * dinv  -> bufB
    gemm_f32<<<(N + 127) / 128, TPB, 0, stream>>>(x, w1, dinv, bufB, N, K1);

    // 5) hidden = relu(dinv*(self+nbrs) + b1) -> bufA
    size_t gthreads = (size_t)N * 32;
    gather_hidden<<<(unsigned)((gthreads + TPB - 1) / TPB), TPB, 0, stream>>>(
        csr, rowptr, cnt, dinv, bufB, b1, bufA, N);

    // 6) hs2 = (hidden @ wcat) * dinv -> bufB
    gemm_f32<<<(N + 127) / 128, TPB, 0, stream>>>(bufA, wcat, dinv, bufB, N, 128);

    // 7) out = dinv*(self+nbrs) + bcat -> mu | logvar
    gather_out<<<(unsigned)((gthreads + TPB - 1) / TPB), TPB, 0, stream>>>(
        csr, rowptr, cnt, dinv, bufB, bcat, out, N);
}

// Round 4
// 635.663 us; speedup vs baseline: 9.2248x; 1.1403x over previous
//
#include <hip/hip_runtime.h>

// GCN-VAE encoder forward on MI355X — R3: split-bf16 MFMA GEMM.
//
// Algebra: agg[d] = dinv[d] * ( hs[d] + sum_{s in N(d)} hs[s] ),  hs := h*dinv
// GEMM: f32 A,B split as hi+lo bf16; A@B ~= Ah@Bh + Ah@Bl + Al@Bh via
// mfma_f32_16x16x32_bf16 (error ~2^-16 relative, << 1.4e-2 threshold).
//
// ws: bufA[N*128] | bufB[N*128] | cnt[N] | dinv[N] | rowptr[N] | cursor[N]
//     | bsum[512] | bcat[128] | w1t_h/l[128*256]s | wcatt_h/l[128*128]s | csr[E]

#define TPB 256

typedef __attribute__((ext_vector_type(8))) short short8;
typedef __attribute__((ext_vector_type(4))) short short4v;
typedef __attribute__((ext_vector_type(4))) float floatx4;

__device__ __forceinline__ void split2(float v, short& hi, short& lo) {
    unsigned u = __float_as_uint(v);
    float hf = __uint_as_float(u & 0xFFFF0000u);
    float lf = v - hf;                       // exact
    hi = (short)(u >> 16);
    lo = (short)(__float_as_uint(lf) >> 16); // truncate: err ~2^-16 rel to v
}

// ---------------- degree ----------------
__global__ void count_kernel(const int* __restrict__ dst, int* __restrict__ cnt, int E) {
    int e = blockIdx.x * TPB + threadIdx.x;
    if (e < E) atomicAdd(&cnt[dst[e]], 1);
}

__global__ void dinv_kernel(const int* __restrict__ cnt, float* __restrict__ dinv, int N) {
    int i = blockIdx.x * TPB + threadIdx.x;
    if (i < N) dinv[i] = rsqrtf(1.0f + (float)cnt[i]);
}

// ---------------- two-level exclusive scan (N <= 512*256) ----------------
__global__ void scan_block(const int* __restrict__ cnt, int* __restrict__ rowptr,
                           int* __restrict__ bsum, int N) {
    __shared__ int sh[TPB];
    int t = threadIdx.x;
    int i = blockIdx.x * TPB + t;
    int v = (i < N) ? cnt[i] : 0;
    sh[t] = v;
    __syncthreads();
#pragma unroll
    for (int off = 1; off < TPB; off <<= 1) {
        int x = (t >= off) ? sh[t - off] : 0;
        __syncthreads();
        sh[t] += x;
        __syncthreads();
    }
    if (i < N) rowptr[i] = sh[t] - v;
    if (t == TPB - 1) bsum[blockIdx.x] = sh[t];
}

__global__ void scan_bsum(int* __restrict__ bsum, int nb) {
    __shared__ int sh[512];
    int t = threadIdx.x;
    int v = (t < nb) ? bsum[t] : 0;
    sh[t] = v;
    __syncthreads();
#pragma unroll
    for (int off = 1; off < 512; off <<= 1) {
        int x = (t >= off) ? sh[t - off] : 0;
        __syncthreads();
        sh[t] += x;
        __syncthreads();
    }
    if (t < nb) bsum[t] = sh[t] - v;
}

__global__ void add_off(int* __restrict__ rowptr, const int* __restrict__ bsum, int N) {
    int i = blockIdx.x * TPB + threadIdx.x;
    if (i < N) rowptr[i] += bsum[blockIdx.x];
}

// ---------------- CSR fill ----------------
__global__ void fill_kernel(const int* __restrict__ src, const int* __restrict__ dst,
                            const int* __restrict__ rowptr, int* __restrict__ cursor,
                            int* __restrict__ csr, int E) {
    int e = blockIdx.x * TPB + threadIdx.x;
    if (e < E) {
        int d = dst[e];
        int p = rowptr[d] + atomicAdd(&cursor[d], 1);
        csr[p] = src[e];
    }
}

// ---------------- weight prep: transpose + hi/lo split ----------------
// w1t[n][k] from w1[k][n], 128x256
__global__ void prep_w1t(const float* __restrict__ w1, short* __restrict__ th,
                         short* __restrict__ tl) {
    int t = blockIdx.x * TPB + threadIdx.x;  // t < 128*256
    int k = t & 255, n = t >> 8;
    float v = w1[(size_t)k * 128 + n];
    short h, l;
    split2(v, h, l);
    th[t] = h;
    tl[t] = l;
}

// wcatt[n][k] (128x128): n<64 -> w2[k][n], else w3[k][n-64]; also bcat
__global__ void prep_wcatt(const float* __restrict__ w2, const float* __restrict__ b2,
                           const float* __restrict__ w3, const float* __restrict__ b3,
                           short* __restrict__ th, short* __restrict__ tl,
                           float* __restrict__ bcat) {
    int t = blockIdx.x * TPB + threadIdx.x;  // t < 128*128
    int k = t & 127, n = t >> 7;
    float v = (n < 64) ? w2[(size_t)k * 64 + n] : w3[(size_t)k * 64 + (n - 64)];
    short h, l;
    split2(v, h, l);
    th[t] = h;
    tl[t] = l;
    if (t < 64) { bcat[t] = b2[t]; bcat[64 + t] = b3[t]; }
}

// ---------------- MFMA GEMM: C[M,128] = (A[M,K] @ B[K,128]) * rs[row] ----------------
// A f32; B pre-split/transposed: Bt[n][k] bf16 hi/lo. BM=64, BN=128, BK=32.
// 4 waves; wave w -> rows [16w,16w+16); 8 n-tiles of 16; 24 MFMA per k-step.
// LDS frag layout [kq][row][8] so each lane's 8 k-elems are one ds_read_b128.
__global__ __launch_bounds__(TPB) void gemm_mfma(const float* __restrict__ A,
                                                 const short* __restrict__ Bth,
                                                 const short* __restrict__ Btl,
                                                 const float* __restrict__ rs,
                                                 float* __restrict__ C, int M, int K) {
    __shared__ short Ah[4 * 64 * 8], Al[4 * 64 * 8];
    __shared__ short Bh[4 * 128 * 8], Bl[4 * 128 * 8];
    int t = threadIdx.x;
    int wave = t >> 6, lane = t & 63, quad = lane >> 4, l16 = lane & 15;
    int bm0 = blockIdx.x * 64;

    floatx4 acc[8];
#pragma unroll
    for (int nt = 0; nt < 8; ++nt) acc[nt] = (floatx4){0.f, 0.f, 0.f, 0.f};

    for (int k0 = 0; k0 < K; k0 += 32) {
        // ---- stage A: 64 rows x 32 k f32 -> hi/lo bf16 ----
#pragma unroll
        for (int i = 0; i < 2; ++i) {
            int c = t + i * 256;           // 0..511
            int row = c >> 3;              // 0..63
            int kc = (c & 7) * 4;          // 0..28
            int gr = bm0 + row;
            float4 v = (gr < M) ? *(const float4*)(A + (size_t)gr * K + k0 + kc)
                                : make_float4(0.f, 0.f, 0.f, 0.f);
            short h0, l0, h1, l1, h2, l2, h3, l3;
            split2(v.x, h0, l0);
            split2(v.y, h1, l1);
            split2(v.z, h2, l2);
            split2(v.w, h3, l3);
            int base = ((kc >> 3) * 64 + row) * 8 + (kc & 7);
            *(short4v*)&Ah[base] = (short4v){h0, h1, h2, h3};
            *(short4v*)&Al[base] = (short4v){l0, l1, l2, l3};
        }
        // ---- stage B: 128 n x 32 k bf16 hi/lo, already [n][k] in global ----
#pragma unroll
        for (int i = 0; i < 2; ++i) {
            int c = t + i * 256;           // 0..511
            int n = c >> 2, kq = c & 3;
            size_t g = (size_t)n * K + k0 + kq * 8;
            int base = (kq * 128 + n) * 8;
            *(short8*)&Bh[base] = *(const short8*)(Bth + g);
            *(short8*)&Bl[base] = *(const short8*)(Btl + g);
        }
        __syncthreads();
        // ---- compute: a_frag m=lane&15(+16w), k=quad*8+j; b_frag n=lane&15(+16nt) ----
        int am = wave * 16 + l16;
        short8 a_h = *(const short8*)&Ah[(quad * 64 + am) * 8];
        short8 a_l = *(const short8*)&Al[(quad * 64 + am) * 8];
#pragma unroll
        for (int nt = 0; nt < 8; ++nt) {
            int bn = nt * 16 + l16;
            short8 b_h = *(const short8*)&Bh[(quad * 128 + bn) * 8];
            short8 b_l = *(const short8*)&Bl[(quad * 128 + bn) * 8];
            acc[nt] = __builtin_amdgcn_mfma_f32_16x16x32_bf16(a_l, b_h, acc[nt], 0, 0, 0);
            acc[nt] = __builtin_amdgcn_mfma_f32_16x16x32_bf16(a_h, b_l, acc[nt], 0, 0, 0);
            acc[nt] = __builtin_amdgcn_mfma_f32_16x16x32_bf16(a_h, b_h, acc[nt], 0, 0, 0);
        }
        __syncthreads();
    }
    // ---- epilogue: D row = quad*4+reg (in wave's 16), col = nt*16 + l16 ----
#pragma unroll
    for (int reg = 0; reg < 4; ++reg) {
        int gr = bm0 + wave * 16 + quad * 4 + reg;
        if (gr < M) {
            float s = rs[gr];
            float* cp = C + (size_t)gr * 128;
#pragma unroll
            for (int nt = 0; nt < 8; ++nt) cp[nt * 16 + l16] = acc[nt][reg] * s;
        }
    }
}

// ---------------- gather layer 1: hidden = relu(dinv*(hs[self]+sum hs[nbr]) + b1) ----------------
__global__ __launch_bounds__(TPB) void gather_hidden(const int* __restrict__ csr,
                                                     const int* __restrict__ rowptr,
                                                     const int* __restrict__ cnt,
                                                     const float* __restrict__ dinv,
                                                     const float* __restrict__ hs,
                                                     const float* __restrict__ b1,
                                                     float* __restrict__ hidden, int N) {
    size_t t = (size_t)blockIdx.x * TPB + threadIdx.x;
    int nid = (int)(t >> 5);
    int lane = threadIdx.x & 31;
    if (nid >= N) return;
    int start = rowptr[nid];
    int deg = cnt[nid];
    const float4* hp = (const float4*)hs;
    float4 acc = hp[(size_t)nid * 32 + lane];
    int j = 0;
    for (; j + 3 < deg; j += 4) {
        int s0 = csr[start + j], s1 = csr[start + j + 1];
        int s2 = csr[start + j + 2], s3 = csr[start + j + 3];
        float4 v0 = hp[(size_t)s0 * 32 + lane];
        float4 v1 = hp[(size_t)s1 * 32 + lane];
        float4 v2 = hp[(size_t)s2 * 32 + lane];
        float4 v3 = hp[(size_t)s3 * 32 + lane];
        acc.x += (v0.x + v1.x) + (v2.x + v3.x);
        acc.y += (v0.y + v1.y) + (v2.y + v3.y);
        acc.z += (v0.z + v1.z) + (v2.z + v3.z);
        acc.w += (v0.w + v1.w) + (v2.w + v3.w);
    }
    for (; j < deg; ++j) {
        int s = csr[start + j];
        float4 v = hp[(size_t)s * 32 + lane];
        acc.x += v.x; acc.y += v.y; acc.z += v.z; acc.w += v.w;
    }
    float di = dinv[nid];
    float4 bb = ((const float4*)b1)[lane];
    float4 r;
    r.x = fmaxf(fmaf(di, acc.x, bb.x), 0.f);
    r.y = fmaxf(fmaf(di, acc.y, bb.y), 0.f);
    r.z = fmaxf(fmaf(di, acc.z, bb.z), 0.f);
    r.w = fmaxf(fmaf(di, acc.w, bb.w), 0.f);
    ((float4*)hidden)[(size_t)nid * 32 + lane] = r;
}

// ---------------- gather layer 2: out = dinv*(hs[self]+sum hs[nbr]) + bcat ----------------
__global__ __launch_bounds__(TPB) void gather_out(const int* __restrict__ csr,
                                                  const int* __restrict__ rowptr,
                                                  const int* __restrict__ cnt,
                                                  const float* __restrict__ dinv,
                                                  const float* __restrict__ hs,
                                                  const float* __restrict__ bcat,
                                                  float* __restrict__ out, int N) {
    size_t t = (size_t)blockIdx.x * TPB + threadIdx.x;
    int nid = (int)(t >> 5);
    int lane = threadIdx.x & 31;
    if (nid >= N) return;
    int start = rowptr[nid];
    int deg = cnt[nid];
    const float4* hp = (const float4*)hs;
    float4 acc = hp[(size_t)nid * 32 + lane];
    int j = 0;
    for (; j + 3 < deg; j += 4) {
        int s0 = csr[start + j], s1 = csr[start + j + 1];
        int s2 = csr[start + j + 2], s3 = csr[start + j + 3];
        float4 v0 = hp[(size_t)s0 * 32 + lane];
        float4 v1 = hp[(size_t)s1 * 32 + lane];
        float4 v2 = hp[(size_t)s2 * 32 + lane];
        float4 v3 = hp[(size_t)s3 * 32 + lane];
        acc.x += (v0.x + v1.x) + (v2.x + v3.x);
        acc.y += (v0.y + v1.y) + (v2.y + v3.y);
        acc.z += (v0.z + v1.z) + (v2.z + v3.z);
        acc.w += (v0.w + v1.w) + (v2.w + v3.w);
    }
    for (; j < deg; ++j) {
        int s = csr[start + j];
        float4 v = hp[(size_t)s * 32 + lane];
        acc.x += v.x; acc.y += v.y; acc.z += v.z; acc.w += v.w;
    }
    float di = dinv[nid];
    float4 bb = ((const float4*)bcat)[lane];
    float4 r;
    r.x = fmaf(di, acc.x, bb.x);
    r.y = fmaf(di, acc.y, bb.y);
    r.z = fmaf(di, acc.z, bb.z);
    r.w = fmaf(di, acc.w, bb.w);
    int f = lane * 4;
    float* dp = (f < 64) ? (out + (size_t)nid * 64 + f)
                         : (out + (size_t)N * 64 + (size_t)nid * 64 + (f - 64));
    *(float4*)dp = r;
}

extern "C" void kernel_launch(void* const* d_in, const int* in_sizes, int n_in,
                              void* d_out, int out_size, void* d_ws, size_t ws_size,
                              hipStream_t stream) {
    const float* x  = (const float*)d_in[0];
    const float* w1 = (const float*)d_in[1];
    const float* b1 = (const float*)d_in[2];
    const float* w2 = (const float*)d_in[3];
    const float* b2 = (const float*)d_in[4];
    const float* w3 = (const float*)d_in[5];
    const float* b3 = (const float*)d_in[6];
    const int*   ei = (const int*)d_in[7];

    const int N = in_sizes[0] / 256;   // 100000
    const int E = in_sizes[7] / 2;     // 1600000
    const int K1 = 256;
    const int nb = (N + TPB - 1) / TPB;

    float* out = (float*)d_out;

    // workspace carve-up
    size_t nh = (size_t)N * 128;
    float* bufA   = (float*)d_ws;          // hidden
    float* bufB   = bufA + nh;             // hs1 / hs2
    int*   cnt    = (int*)(bufB + nh);
    float* dinv   = (float*)(cnt + N);
    int*   rowptr = (int*)(dinv + N);
    int*   cursor = rowptr + N;
    int*   bsum   = cursor + N;
    float* bcat   = (float*)(bsum + 512);
    short* w1t_h  = (short*)(bcat + 128);
    short* w1t_l  = w1t_h + 128 * 256;
    short* wct_h  = w1t_l + 128 * 256;
    short* wct_l  = wct_h + 128 * 128;
    int*   csr    = (int*)(wct_l + 128 * 128);

    const int* srcp = ei;
    const int* dstp = ei + E;

    // 0) zero counters
    hipMemsetAsync(cnt, 0, (size_t)N * sizeof(int), stream);
    hipMemsetAsync(cursor, 0, (size_t)N * sizeof(int), stream);

    // 1) degree + dinv
    count_kernel<<<(E + TPB - 1) / TPB, TPB, 0, stream>>>(dstp, cnt, E);
    dinv_kernel<<<(N + TPB - 1) / TPB, TPB, 0, stream>>>(cnt, dinv, N);

    // 2) CSR build
    scan_block<<<nb, TPB, 0, stream>>>(cnt, rowptr, bsum, N);
    scan_bsum<<<1, 512, 0, stream>>>(bsum, nb);
    add_off<<<nb, TPB, 0, stream>>>(rowptr, bsum, N);
    fill_kernel<<<(E + TPB - 1) / TPB, TPB, 0, stream>>>(srcp, dstp, rowptr, cursor, csr, E);

    // 3) weight prep (transpose + split)
    prep_w1t<<<(128 * 256) / TPB, TPB, 0, stream>>>(w1, w1t_h, w1t_l);
    prep_wcatt<<<(128 * 128) / TPB, TPB, 0, stream>>>(w2, b2, w3, b3, wct_h, wct_l, bcat);

    // 4) hs1 = (x @ w1) * dinv  -> bufB
    gemm_mfma<<<(N + 63) / 64, TPB, 0, stream>>>(x, w1t_h, w1t_l, dinv, bufB, N, K1);

    // 5) hidden = relu(dinv*(self+nbrs) + b1) -> bufA
    size_t gthreads = (size_t)N * 32;
    gather_hidden<<<(unsigned)((gthreads + TPB - 1) / TPB), TPB, 0, stream>>>(
        csr, rowptr, cnt, dinv, bufB, b1, bufA, N);

    // 6) hs2 = (hidden @ wcat) * dinv -> bufB
    gemm_mfma<<<(N + 63) / 64, TPB, 0, stream>>>(bufA, wct_h, wct_l, dinv, bufB, N, 128);

    // 7) out = dinv*(self+nbrs) + bcat -> mu | logvar
    gather_out<<<(unsigned)((gthreads + TPB - 1) / TPB), TPB, 0, stream>>>(
        csr, rowptr, cnt, dinv, bufB, bcat, out, N);
}

// Round 5
// 530.178 us; speedup vs baseline: 11.0602x; 1.1990x over previous
//
#include <hip/hip_runtime.h>

// GCN-VAE encoder forward on MI355X — R4: bf16 activation rows.
//
// agg[d] = dinv[d] * ( hs[d] + sum_{s in N(d)} hs[s] ),  hs := h*dinv
// hs1, hs2 stored bf16 (RTN) -> gather traffic halves.
// hidden stored as bf16 hi+lo (exact split) -> GEMM2 keeps 3-term precision.
//
// ws: hs1[N*128]bf | hidH[N*128]bf | hidL[N*128]bf | hs2[N*128]bf | cnt[N] |
//     dinv[N] | rowptr[N] | cursor[N] | bsum[512] | bcat[128] |
//     w1t_h/l[128*256]bf | wct_h/l[128*128]bf | csr[E]

#define TPB 256

typedef __attribute__((ext_vector_type(8))) short short8;
typedef __attribute__((ext_vector_type(4))) short short4v;
typedef __attribute__((ext_vector_type(4))) float floatx4;

__device__ __forceinline__ void split2(float v, short& hi, short& lo) {
    unsigned u = __float_as_uint(v);
    float hf = __uint_as_float(u & 0xFFFF0000u);
    float lf = v - hf;                       // exact
    hi = (short)(u >> 16);
    lo = (short)(__float_as_uint(lf) >> 16);
}

__device__ __forceinline__ short bf16_rtn(float v) {
    unsigned u = __float_as_uint(v);
    u += 0x7FFF + ((u >> 16) & 1);           // round to nearest even
    return (short)(u >> 16);
}

__device__ __forceinline__ void addrow(float* a, uint4 v) {
    a[0] += __uint_as_float(v.x << 16); a[1] += __uint_as_float(v.x & 0xFFFF0000u);
    a[2] += __uint_as_float(v.y << 16); a[3] += __uint_as_float(v.y & 0xFFFF0000u);
    a[4] += __uint_as_float(v.z << 16); a[5] += __uint_as_float(v.z & 0xFFFF0000u);
    a[6] += __uint_as_float(v.w << 16); a[7] += __uint_as_float(v.w & 0xFFFF0000u);
}

// ---------------- degree ----------------
__global__ void count_kernel(const int* __restrict__ dst, int* __restrict__ cnt, int E) {
    int e = blockIdx.x * TPB + threadIdx.x;
    if (e < E) atomicAdd(&cnt[dst[e]], 1);
}

__global__ void dinv_kernel(const int* __restrict__ cnt, float* __restrict__ dinv, int N) {
    int i = blockIdx.x * TPB + threadIdx.x;
    if (i < N) dinv[i] = rsqrtf(1.0f + (float)cnt[i]);
}

// ---------------- two-level exclusive scan ----------------
__global__ void scan_block(const int* __restrict__ cnt, int* __restrict__ rowptr,
                           int* __restrict__ bsum, int N) {
    __shared__ int sh[TPB];
    int t = threadIdx.x;
    int i = blockIdx.x * TPB + t;
    int v = (i < N) ? cnt[i] : 0;
    sh[t] = v;
    __syncthreads();
#pragma unroll
    for (int off = 1; off < TPB; off <<= 1) {
        int x = (t >= off) ? sh[t - off] : 0;
        __syncthreads();
        sh[t] += x;
        __syncthreads();
    }
    if (i < N) rowptr[i] = sh[t] - v;
    if (t == TPB - 1) bsum[blockIdx.x] = sh[t];
}

__global__ void scan_bsum(int* __restrict__ bsum, int nb) {
    __shared__ int sh[512];
    int t = threadIdx.x;
    int v = (t < nb) ? bsum[t] : 0;
    sh[t] = v;
    __syncthreads();
#pragma unroll
    for (int off = 1; off < 512; off <<= 1) {
        int x = (t >= off) ? sh[t - off] : 0;
        __syncthreads();
        sh[t] += x;
        __syncthreads();
    }
    if (t < nb) bsum[t] = sh[t] - v;
}

__global__ void add_off(int* __restrict__ rowptr, const int* __restrict__ bsum, int N) {
    int i = blockIdx.x * TPB + threadIdx.x;
    if (i < N) rowptr[i] += bsum[blockIdx.x];
}

// ---------------- CSR fill ----------------
__global__ void fill_kernel(const int* __restrict__ src, const int* __restrict__ dst,
                            const int* __restrict__ rowptr, int* __restrict__ cursor,
                            int* __restrict__ csr, int E) {
    int e = blockIdx.x * TPB + threadIdx.x;
    if (e < E) {
        int d = dst[e];
        int p = rowptr[d] + atomicAdd(&cursor[d], 1);
        csr[p] = src[e];
    }
}

// ---------------- weight prep: transpose + hi/lo split ----------------
__global__ void prep_w1t(const float* __restrict__ w1, short* __restrict__ th,
                         short* __restrict__ tl) {
    int t = blockIdx.x * TPB + threadIdx.x;  // t < 128*256
    int k = t & 255, n = t >> 8;
    float v = w1[(size_t)k * 128 + n];
    short h, l;
    split2(v, h, l);
    th[t] = h;
    tl[t] = l;
}

__global__ void prep_wcatt(const float* __restrict__ w2, const float* __restrict__ b2,
                           const float* __restrict__ w3, const float* __restrict__ b3,
                           short* __restrict__ th, short* __restrict__ tl,
                           float* __restrict__ bcat) {
    int t = blockIdx.x * TPB + threadIdx.x;  // t < 128*128
    int k = t & 127, n = t >> 7;
    float v = (n < 64) ? w2[(size_t)k * 64 + n] : w3[(size_t)k * 64 + (n - 64)];
    short h, l;
    split2(v, h, l);
    th[t] = h;
    tl[t] = l;
    if (t < 64) { bcat[t] = b2[t]; bcat[64 + t] = b3[t]; }
}

// ---------------- MFMA GEMM1: Cb[M,128](bf16) = (A_f32[M,K] @ B) * rs[row] ----------------
// BM=64, BN=128, BK=32; 4 waves; 24 MFMA/k-step. LDS frag layout [kq][row][8].
__global__ __launch_bounds__(TPB) void gemm_mfma_f32in(const float* __restrict__ A,
                                                       const short* __restrict__ Bth,
                                                       const short* __restrict__ Btl,
                                                       const float* __restrict__ rs,
                                                       short* __restrict__ Cb, int M, int K) {
    __shared__ short Ah[4 * 64 * 8], Al[4 * 64 * 8];
    __shared__ short Bh[4 * 128 * 8], Bl[4 * 128 * 8];
    int t = threadIdx.x;
    int wave = t >> 6, lane = t & 63, quad = lane >> 4, l16 = lane & 15;
    int bm0 = blockIdx.x * 64;

    floatx4 acc[8];
#pragma unroll
    for (int nt = 0; nt < 8; ++nt) acc[nt] = (floatx4){0.f, 0.f, 0.f, 0.f};

    for (int k0 = 0; k0 < K; k0 += 32) {
        // stage A: 64 rows x 32 k f32 -> hi/lo bf16
#pragma unroll
        for (int i = 0; i < 2; ++i) {
            int c = t + i * 256;
            int row = c >> 3;
            int kc = (c & 7) * 4;
            int gr = bm0 + row;
            float4 v = (gr < M) ? *(const float4*)(A + (size_t)gr * K + k0 + kc)
                                : make_float4(0.f, 0.f, 0.f, 0.f);
            short h0, l0, h1, l1, h2, l2, h3, l3;
            split2(v.x, h0, l0);
            split2(v.y, h1, l1);
            split2(v.z, h2, l2);
            split2(v.w, h3, l3);
            int base = ((kc >> 3) * 64 + row) * 8 + (kc & 7);
            *(short4v*)&Ah[base] = (short4v){h0, h1, h2, h3};
            *(short4v*)&Al[base] = (short4v){l0, l1, l2, l3};
        }
        // stage B: already [n][k] bf16 hi/lo in global
#pragma unroll
        for (int i = 0; i < 2; ++i) {
            int c = t + i * 256;
            int n = c >> 2, kq = c & 3;
            size_t g = (size_t)n * K + k0 + kq * 8;
            int base = (kq * 128 + n) * 8;
            *(short8*)&Bh[base] = *(const short8*)(Bth + g);
            *(short8*)&Bl[base] = *(const short8*)(Btl + g);
        }
        __syncthreads();
        int am = wave * 16 + l16;
        short8 a_h = *(const short8*)&Ah[(quad * 64 + am) * 8];
        short8 a_l = *(const short8*)&Al[(quad * 64 + am) * 8];
#pragma unroll
        for (int nt = 0; nt < 8; ++nt) {
            int bn = nt * 16 + l16;
            short8 b_h = *(const short8*)&Bh[(quad * 128 + bn) * 8];
            short8 b_l = *(const short8*)&Bl[(quad * 128 + bn) * 8];
            acc[nt] = __builtin_amdgcn_mfma_f32_16x16x32_bf16(a_l, b_h, acc[nt], 0, 0, 0);
            acc[nt] = __builtin_amdgcn_mfma_f32_16x16x32_bf16(a_h, b_l, acc[nt], 0, 0, 0);
            acc[nt] = __builtin_amdgcn_mfma_f32_16x16x32_bf16(a_h, b_h, acc[nt], 0, 0, 0);
        }
        __syncthreads();
    }
#pragma unroll
    for (int reg = 0; reg < 4; ++reg) {
        int gr = bm0 + wave * 16 + quad * 4 + reg;
        if (gr < M) {
            float s = rs[gr];
            short* cp = Cb + (size_t)gr * 128;
#pragma unroll
            for (int nt = 0; nt < 8; ++nt) cp[nt * 16 + l16] = bf16_rtn(acc[nt][reg] * s);
        }
    }
}

// ---------------- MFMA GEMM2: Cb[M,128](bf16) = ((AH+AL)[M,K] @ B) * rs ----------------
// A pre-split bf16 hi/lo, layout [row][k]. K=128 here.
__global__ __launch_bounds__(TPB) void gemm_mfma_bfin(const short* __restrict__ AH,
                                                      const short* __restrict__ AL,
                                                      const short* __restrict__ Bth,
                                                      const short* __restrict__ Btl,
                                                      const float* __restrict__ rs,
                                                      short* __restrict__ Cb, int M, int K) {
    __shared__ short Ah[4 * 64 * 8], Al[4 * 64 * 8];
    __shared__ short Bh[4 * 128 * 8], Bl[4 * 128 * 8];
    int t = threadIdx.x;
    int wave = t >> 6, lane = t & 63, quad = lane >> 4, l16 = lane & 15;
    int bm0 = blockIdx.x * 64;

    floatx4 acc[8];
#pragma unroll
    for (int nt = 0; nt < 8; ++nt) acc[nt] = (floatx4){0.f, 0.f, 0.f, 0.f};

    for (int k0 = 0; k0 < K; k0 += 32) {
        // stage A: 64 rows x 32 k, straight uint4 copies of hi and lo
        {
            int row = t >> 2, kc = (t & 3) * 8;
            int gr = bm0 + row;
            uint4 vh = make_uint4(0u, 0u, 0u, 0u), vl = vh;
            if (gr < M) {
                size_t g = (size_t)gr * K + k0 + kc;
                vh = *(const uint4*)(AH + g);
                vl = *(const uint4*)(AL + g);
            }
            int base = ((kc >> 3) * 64 + row) * 8;
            *(uint4*)&Ah[base] = vh;
            *(uint4*)&Al[base] = vl;
        }
        // stage B
#pragma unroll
        for (int i = 0; i < 2; ++i) {
            int c = t + i * 256;
            int n = c >> 2, kq = c & 3;
            size_t g = (size_t)n * K + k0 + kq * 8;
            int base = (kq * 128 + n) * 8;
            *(short8*)&Bh[base] = *(const short8*)(Bth + g);
            *(short8*)&Bl[base] = *(const short8*)(Btl + g);
        }
        __syncthreads();
        int am = wave * 16 + l16;
        short8 a_h = *(const short8*)&Ah[(quad * 64 + am) * 8];
        short8 a_l = *(const short8*)&Al[(quad * 64 + am) * 8];
#pragma unroll
        for (int nt = 0; nt < 8; ++nt) {
            int bn = nt * 16 + l16;
            short8 b_h = *(const short8*)&Bh[(quad * 128 + bn) * 8];
            short8 b_l = *(const short8*)&Bl[(quad * 128 + bn) * 8];
            acc[nt] = __builtin_amdgcn_mfma_f32_16x16x32_bf16(a_l, b_h, acc[nt], 0, 0, 0);
            acc[nt] = __builtin_amdgcn_mfma_f32_16x16x32_bf16(a_h, b_l, acc[nt], 0, 0, 0);
            acc[nt] = __builtin_amdgcn_mfma_f32_16x16x32_bf16(a_h, b_h, acc[nt], 0, 0, 0);
        }
        __syncthreads();
    }
#pragma unroll
    for (int reg = 0; reg < 4; ++reg) {
        int gr = bm0 + wave * 16 + quad * 4 + reg;
        if (gr < M) {
            float s = rs[gr];
            short* cp = Cb + (size_t)gr * 128;
#pragma unroll
            for (int nt = 0; nt < 8; ++nt) cp[nt * 16 + l16] = bf16_rtn(acc[nt][reg] * s);
        }
    }
}

// ---------------- gather 1: hidden = relu(dinv*(self+sum nbrs) + b1) -> bf16 hi/lo ----------------
// 16 lanes per node; each lane covers 8 cols (one uint4 of bf16).
__global__ __launch_bounds__(TPB) void gather_hidden(const int* __restrict__ csr,
                                                     const int* __restrict__ rowptr,
                                                     const int* __restrict__ cnt,
                                                     const float* __restrict__ dinv,
                                                     const short* __restrict__ hs,
                                                     const float* __restrict__ b1,
                                                     short* __restrict__ hidH,
                                                     short* __restrict__ hidL, int N) {
    size_t t = (size_t)blockIdx.x * TPB + threadIdx.x;
    int nid = (int)(t >> 4);
    int lane = threadIdx.x & 15;
    if (nid >= N) return;
    int start = rowptr[nid];
    int deg = cnt[nid];
    const uint4* hp = (const uint4*)hs;  // row = 16 uint4
    float acc[8] = {0, 0, 0, 0, 0, 0, 0, 0};
    addrow(acc, hp[(size_t)nid * 16 + lane]);  // self term
    int j = 0;
    for (; j + 1 < deg; j += 2) {
        int s0 = csr[start + j], s1 = csr[start + j + 1];
        uint4 v0 = hp[(size_t)s0 * 16 + lane];
        uint4 v1 = hp[(size_t)s1 * 16 + lane];
        addrow(acc, v0);
        addrow(acc, v1);
    }
    if (j < deg) addrow(acc, hp[(size_t)csr[start + j] * 16 + lane]);
    float di = dinv[nid];
    float4 b0 = ((const float4*)b1)[lane * 2];
    float4 b1v = ((const float4*)b1)[lane * 2 + 1];
    float bb[8] = {b0.x, b0.y, b0.z, b0.w, b1v.x, b1v.y, b1v.z, b1v.w};
    unsigned hiw[8];
    short low[8];
#pragma unroll
    for (int i = 0; i < 8; ++i) {
        float h = fmaxf(fmaf(di, acc[i], bb[i]), 0.f);
        unsigned u = __float_as_uint(h);
        hiw[i] = u >> 16;
        float hf = __uint_as_float(u & 0xFFFF0000u);
        low[i] = bf16_rtn(h - hf);
    }
    uint4 ph, pl;
    ph.x = hiw[0] | (hiw[1] << 16);
    ph.y = hiw[2] | (hiw[3] << 16);
    ph.z = hiw[4] | (hiw[5] << 16);
    ph.w = hiw[6] | (hiw[7] << 16);
    pl.x = (unsigned short)low[0] | ((unsigned)(unsigned short)low[1] << 16);
    pl.y = (unsigned short)low[2] | ((unsigned)(unsigned short)low[3] << 16);
    pl.z = (unsigned short)low[4] | ((unsigned)(unsigned short)low[5] << 16);
    pl.w = (unsigned short)low[6] | ((unsigned)(unsigned short)low[7] << 16);
    ((uint4*)hidH)[(size_t)nid * 16 + lane] = ph;
    ((uint4*)hidL)[(size_t)nid * 16 + lane] = pl;
}

// ---------------- gather 2: out = dinv*(self+sum nbrs) + bcat -> f32 mu|logvar ----------------
__global__ __launch_bounds__(TPB) void gather_out(const int* __restrict__ csr,
                                                  const int* __restrict__ rowptr,
                                                  const int* __restrict__ cnt,
                                                  const float* __restrict__ dinv,
                                                  const short* __restrict__ hs,
                                                  const float* __restrict__ bcat,
                                                  float* __restrict__ out, int N) {
    size_t t = (size_t)blockIdx.x * TPB + threadIdx.x;
    int nid = (int)(t >> 4);
    int lane = threadIdx.x & 15;
    if (nid >= N) return;
    int start = rowptr[nid];
    int deg = cnt[nid];
    const uint4* hp = (const uint4*)hs;
    float acc[8] = {0, 0, 0, 0, 0, 0, 0, 0};
    addrow(acc, hp[(size_t)nid * 16 + lane]);
    int j = 0;
    for (; j + 1 < deg; j += 2) {
        int s0 = csr[start + j], s1 = csr[start + j + 1];
        uint4 v0 = hp[(size_t)s0 * 16 + lane];
        uint4 v1 = hp[(size_t)s1 * 16 + lane];
        addrow(acc, v0);
        addrow(acc, v1);
    }
    if (j < deg) addrow(acc, hp[(size_t)csr[start + j] * 16 + lane]);
    float di = dinv[nid];
    float4 b0 = ((const float4*)bcat)[lane * 2];
    float4 b1v = ((const float4*)bcat)[lane * 2 + 1];
    float4 r0, r1;
    r0.x = fmaf(di, acc[0], b0.x);
    r0.y = fmaf(di, acc[1], b0.y);
    r0.z = fmaf(di, acc[2], b0.z);
    r0.w = fmaf(di, acc[3], b0.w);
    r1.x = fmaf(di, acc[4], b1v.x);
    r1.y = fmaf(di, acc[5], b1v.y);
    r1.z = fmaf(di, acc[6], b1v.z);
    r1.w = fmaf(di, acc[7], b1v.w);
    int f = lane * 8;  // 0..120
    float* dp = (f < 64) ? (out + (size_t)nid * 64 + f)
                         : (out + (size_t)N * 64 + (size_t)nid * 64 + (f - 64));
    *(float4*)dp = r0;
    *(float4*)(dp + 4) = r1;
}

extern "C" void kernel_launch(void* const* d_in, const int* in_sizes, int n_in,
                              void* d_out, int out_size, void* d_ws, size_t ws_size,
                              hipStream_t stream) {
    const float* x  = (const float*)d_in[0];
    const float* w1 = (const float*)d_in[1];
    const float* b1 = (const float*)d_in[2];
    const float* w2 = (const float*)d_in[3];
    const float* b2 = (const float*)d_in[4];
    const float* w3 = (const float*)d_in[5];
    const float* b3 = (const float*)d_in[6];
    const int*   ei = (const int*)d_in[7];

    const int N = in_sizes[0] / 256;   // 100000
    const int E = in_sizes[7] / 2;     // 1600000
    const int K1 = 256;
    const int nb = (N + TPB - 1) / TPB;

    float* out = (float*)d_out;

    // workspace carve-up
    size_t nh = (size_t)N * 128;
    short* hs1    = (short*)d_ws;          // N*128 bf16
    short* hidH   = hs1 + nh;
    short* hidL   = hidH + nh;
    short* hs2    = hidL + nh;
    int*   cnt    = (int*)(hs2 + nh);
    float* dinv   = (float*)(cnt + N);
    int*   rowptr = (int*)(dinv + N);
    int*   cursor = rowptr + N;
    int*   bsum   = cursor + N;
    float* bcat   = (float*)(bsum + 512);
    short* w1t_h  = (short*)(bcat + 128);
    short* w1t_l  = w1t_h + 128 * 256;
    short* wct_h  = w1t_l + 128 * 256;
    short* wct_l  = wct_h + 128 * 128;
    int*   csr    = (int*)(wct_l + 128 * 128);

    const int* srcp = ei;
    const int* dstp = ei + E;

    // 0) zero counters
    hipMemsetAsync(cnt, 0, (size_t)N * sizeof(int), stream);
    hipMemsetAsync(cursor, 0, (size_t)N * sizeof(int), stream);

    // 1) degree + dinv
    count_kernel<<<(E + TPB - 1) / TPB, TPB, 0, stream>>>(dstp, cnt, E);
    dinv_kernel<<<(N + TPB - 1) / TPB, TPB, 0, stream>>>(cnt, dinv, N);

    // 2) CSR build
    scan_block<<<nb, TPB, 0, stream>>>(cnt, rowptr, bsum, N);
    scan_bsum<<<1, 512, 0, stream>>>(bsum, nb);
    add_off<<<nb, TPB, 0, stream>>>(rowptr, bsum, N);
    fill_kernel<<<(E + TPB - 1) / TPB, TPB, 0, stream>>>(srcp, dstp, rowptr, cursor, csr, E);

    // 3) weight prep
    prep_w1t<<<(128 * 256) / TPB, TPB, 0, stream>>>(w1, w1t_h, w1t_l);
    prep_wcatt<<<(128 * 128) / TPB, TPB, 0, stream>>>(w2, b2, w3, b3, wct_h, wct_l, bcat);

    // 4) hs1 = (x @ w1) * dinv  -> bf16
    gemm_mfma_f32in<<<(N + 63) / 64, TPB, 0, stream>>>(x, w1t_h, w1t_l, dinv, hs1, N, K1);

    // 5) hidden = relu(dinv*(self+nbrs) + b1) -> hi/lo bf16
    size_t gthreads = (size_t)N * 16;
    gather_hidden<<<(unsigned)((gthreads + TPB - 1) / TPB), TPB, 0, stream>>>(
        csr, rowptr, cnt, dinv, hs1, b1, hidH, hidL, N);

    // 6) hs2 = (hidden @ wcat) * dinv -> bf16
    gemm_mfma_bfin<<<(N + 63) / 64, TPB, 0, stream>>>(hidH, hidL, wct_h, wct_l, dinv, hs2, N, 128);

    // 7) out = dinv*(self+nbrs) + bcat -> mu | logvar (f32)
    gather_out<<<(unsigned)((gthreads + TPB - 1) / TPB), TPB, 0, stream>>>(
        csr, rowptr, cnt, dinv, hs2, bcat, out, N);
}